// Round 15
// baseline (399.833 us; speedup 1.0000x reference)
//
#include <hip/hip_runtime.h>
#include <hip/hip_bf16.h>
#include <math.h>

#define DIM 2048
#define NH 16
#define HD 128
#define BATCH 2
#define SEQ 2048
#define TOKENS (BATCH * SEQ)   // 4096
#define NQKV (DIM + 2 * HD)    // 2304

typedef __attribute__((ext_vector_type(8))) _Float16 f16x8;
typedef __attribute__((ext_vector_type(4))) float f32x4;
typedef unsigned short u16;
typedef unsigned int u32;

typedef union { u32 d[4]; f16x8 v; } frag_u;

__device__ __forceinline__ u16 f2h(float f) {
    union { _Float16 h; u16 u; } v; v.h = (_Float16)f; return v.u;
}
__device__ __forceinline__ void gll16(const void* g, void* l) {
    __builtin_amdgcn_global_load_lds(
        (const __attribute__((address_space(1))) unsigned int*)g,
        (__attribute__((address_space(3))) unsigned int*)l, 16, 0, 0);
}

// ---------------------------------------------------------------------------
// prep kernels (unchanged)
// ---------------------------------------------------------------------------
__global__ __launch_bounds__(256) void conv_f16(
    const float* __restrict__ in, u16* __restrict__ out)
{
    const int i = blockIdx.x * 256 + threadIdx.x;
    const float4 v = ((const float4*)in)[i];
    ushort4 h;
    h.x = f2h(v.x); h.y = f2h(v.y); h.z = f2h(v.z); h.w = f2h(v.w);
    ((ushort4*)out)[i] = h;
}

__global__ __launch_bounds__(256) void transpose_f16(
    const float* __restrict__ W, u16* __restrict__ T, int K, int N, int rowoff)
{
    __shared__ float tile[32][33];
    const int k0 = blockIdx.x * 32;
    const int n0 = blockIdx.y * 32;
    const int tid = threadIdx.x;
#pragma unroll
    for (int i = 0; i < 4; ++i) {
        const int idx = tid + i * 256;
        const int r = idx >> 5, c = idx & 31;
        tile[r][c] = W[(size_t)(k0 + r) * N + n0 + c];
    }
    __syncthreads();
#pragma unroll
    for (int i = 0; i < 4; ++i) {
        const int idx = tid + i * 256;
        const int r = idx >> 5, c = idx & 31;
        T[(size_t)(rowoff + n0 + r) * K + k0 + c] = f2h(tile[c][r]);
    }
}

__global__ __launch_bounds__(256) void concat_bias(
    const float* __restrict__ bq, const float* __restrict__ bk,
    const float* __restrict__ bv, float* __restrict__ bc)
{
    const int i = blockIdx.x * 256 + threadIdx.x;
    float v;
    if (i < DIM) v = bq[i];
    else if (i < DIM + HD) v = bk[i - DIM];
    else v = bv[i - DIM - HD];
    bc[i] = v;
}

// ---------------------------------------------------------------------------
// fp16 GEMM (unchanged r8/r10 structure): 128x128 tile, BK=32, 2-buffer LDS.
// ---------------------------------------------------------------------------
template <int MODE>
__global__ __launch_bounds__(256) void gemm_f16(
    const u16* __restrict__ A, const u16* __restrict__ B,
    const float* __restrict__ bias, float* __restrict__ Cf,
    u16* __restrict__ qdst, u16* __restrict__ kdst, u16* __restrict__ vtdst,
    float scale)
{
    constexpr int BK = 32;
    __shared__ u16 lds[2][2 * 128 * BK];

    const int tid = threadIdx.x;
    const int wid = tid >> 6;
    const int lane = tid & 63;
    const int lr = lane & 15;
    const int lhi = lane >> 4;
    const int wr = wid >> 1, wc = wid & 1;
    const int bm = blockIdx.y * 128;
    const int bn = blockIdx.x * 128;

    f32x4 acc[4][4];
#pragma unroll
    for (int i = 0; i < 4; ++i)
#pragma unroll
        for (int j = 0; j < 4; ++j) acc[i][j] = (f32x4){0.f, 0.f, 0.f, 0.f};

#define STAGE(buf_, k0_)                                                      \
    {                                                                         \
        _Pragma("unroll")                                                     \
        for (int rr = 0; rr < 2; ++rr) {                                      \
            const int slot = rr * 256 + tid;                                  \
            const int row = slot >> 2;                                        \
            const int gch = ((slot & 3) ^ ((row >> 1) & 3)) * 8;              \
            char* lbase = (char*)lds[buf_] + (size_t)(rr * 256 + wid * 64) * 16; \
            gll16(A + (size_t)(bm + row) * DIM + (k0_) + gch, lbase);         \
            gll16(B + (size_t)(bn + row) * DIM + (k0_) + gch, lbase + 8192);  \
        }                                                                     \
    }

    STAGE(0, 0);
    __syncthreads();

    int cur = 0;
    for (int k0 = 0; k0 < DIM; k0 += BK) {
        if (k0 + BK < DIM) STAGE(cur ^ 1, k0 + BK);

        f16x8 a[4], b[4];
#pragma unroll
        for (int i = 0; i < 4; ++i) {
            const int mrow = wr * 64 + i * 16 + lr;
            const int nrow = wc * 64 + i * 16 + lr;
            a[i] = *(const f16x8*)&lds[cur][mrow * BK + ((lhi ^ ((mrow >> 1) & 3)) * 8)];
            b[i] = *(const f16x8*)&lds[cur][4096 + nrow * BK + ((lhi ^ ((nrow >> 1) & 3)) * 8)];
        }
        __builtin_amdgcn_s_setprio(1);
#pragma unroll
        for (int i = 0; i < 4; ++i)
#pragma unroll
            for (int j = 0; j < 4; ++j)
                acc[i][j] = __builtin_amdgcn_mfma_f32_16x16x32_f16(a[i], b[j], acc[i][j], 0, 0, 0);
        __builtin_amdgcn_s_setprio(0);
        __syncthreads();
        cur ^= 1;
    }
#undef STAGE

    const float alpha = (MODE == 0 && bn < DIM) ? scale : 1.0f;
    float bj[4];
#pragma unroll
    for (int j = 0; j < 4; ++j) bj[j] = bias[bn + wc * 64 + j * 16 + lr];

#pragma unroll
    for (int i = 0; i < 4; ++i) {
#pragma unroll
        for (int j = 0; j < 4; ++j) {
#pragma unroll
            for (int r = 0; r < 4; ++r) {
                const int row = bm + wr * 64 + i * 16 + lhi * 4 + r;
                const int col = bn + wc * 64 + j * 16 + lr;
                const float val = (acc[i][j][r] + bj[j]) * alpha;
                if (MODE == 1) {
                    Cf[(size_t)row * DIM + col] = val;
                } else if (bn < DIM) {
                    qdst[(size_t)row * DIM + col] = f2h(val);
                } else if (bn < DIM + HD) {
                    kdst[(size_t)row * HD + (col - DIM)] = f2h(val);
                } else {
                    vtdst[(size_t)(col - DIM - HD) * TOKENS + row] = f2h(val);
                }
            }
        }
    }
}

// ---------------------------------------------------------------------------
// MQA flash attention, L2-DIRECT (no LDS, no barriers):
// K/V per batch = 1 MB total -> L2-resident; per-iteration tile working set
// (16KB K + 16KB V) is L1-resident and shared by the block's 4 waves
// (Common-mistake #7 / m169: don't LDS-stage data that cache-fits).
// Body = r8's validated in-order swapped-QK^T + butterfly + defer-max;
// fragment reads go straight to global.  Waves run fully unsynchronized.
// ---------------------------------------------------------------------------
__global__ __launch_bounds__(256, 2) void mqa_attn_f16(
    const u16* __restrict__ Q, const u16* __restrict__ Kg,
    const u16* __restrict__ Vtg, u16* __restrict__ Oh)
{
    const int tid = threadIdx.x;
    const int wid = tid >> 6;
    const int lane = tid & 63;
    const int lr = lane & 15;
    const int lhi = lane >> 4;
    const bool l5 = (lhi & 2) != 0;

    const int qt = blockIdx.x;
    const int h  = blockIdx.y;
    const int b  = blockIdx.z;
    const size_t bseq = (size_t)b * SEQ;
    const int q0 = qt * 128 + wid * 32;

    f16x8 qf[2][4];
#pragma unroll
    for (int mt = 0; mt < 2; ++mt) {
        const u16* qrow = Q + (bseq + q0 + mt * 16 + lr) * DIM + (size_t)h * HD;
#pragma unroll
        for (int kk = 0; kk < 4; ++kk)
            qf[mt][kk] = *(const f16x8*)(qrow + kk * 32 + lhi * 8);
    }

    f16x8 ones;
#pragma unroll
    for (int j = 0; j < 8; ++j) ones[j] = (_Float16)1.0f;

    f32x4 o[2][8];
#pragma unroll
    for (int mt = 0; mt < 2; ++mt)
#pragma unroll
        for (int dt = 0; dt < 8; ++dt) o[mt][dt] = (f32x4){0.f, 0.f, 0.f, 0.f};
    float m[2]    = {-INFINITY, -INFINITY};
    float lsum[2] = {0.f, 0.f};

    // per-lane base pointers; loop adds uniform t0 offsets
    const u16* kp = Kg + (bseq + lr) * HD + lhi * 8;            // row lr, chunk lhi
    const u16* vp = Vtg + (size_t)lr * TOKENS + bseq + lhi * 8; // d-row lr, col chunk

    for (int t0 = 0; t0 < SEQ; t0 += 64) {
        // ---- QK_t (swapped): sc[mt][ct] = S^T[kv=ct*16+lhi*4+r][q] ----
        f32x4 sc[2][4];
#pragma unroll
        for (int mt = 0; mt < 2; ++mt)
#pragma unroll
            for (int ct = 0; ct < 4; ++ct) sc[mt][ct] = (f32x4){0.f, 0.f, 0.f, 0.f};
        __builtin_amdgcn_s_setprio(1);
#pragma unroll
        for (int kk = 0; kk < 4; ++kk)
#pragma unroll
            for (int ct = 0; ct < 4; ++ct) {
                const f16x8 kf =
                    *(const f16x8*)(kp + (size_t)(t0 + ct * 16) * HD + kk * 32);
                sc[0][ct] = __builtin_amdgcn_mfma_f32_16x16x32_f16(kf, qf[0][kk], sc[0][ct], 0, 0, 0);
                sc[1][ct] = __builtin_amdgcn_mfma_f32_16x16x32_f16(kf, qf[1][kk], sc[1][ct], 0, 0, 0);
            }
        __builtin_amdgcn_s_setprio(0);

        // ---- softmax + pack/butterfly, per m-tile (r8-validated) ----
        frag_u pa[2][2];
        float al[2];
#pragma unroll
        for (int mt = 0; mt < 2; ++mt) {
            float pm = fmaxf(fmaxf(fmaxf(sc[mt][0][0], sc[mt][0][1]),
                                   fmaxf(sc[mt][0][2], sc[mt][0][3])),
                             fmaxf(fmaxf(sc[mt][1][0], sc[mt][1][1]),
                                   fmaxf(sc[mt][1][2], sc[mt][1][3])));
            pm = fmaxf(pm, fmaxf(fmaxf(fmaxf(sc[mt][2][0], sc[mt][2][1]),
                                       fmaxf(sc[mt][2][2], sc[mt][2][3])),
                                 fmaxf(fmaxf(sc[mt][3][0], sc[mt][3][1]),
                                       fmaxf(sc[mt][3][2], sc[mt][3][3]))));
            pm = fmaxf(pm, __shfl_xor(pm, 16));
            pm = fmaxf(pm, __shfl_xor(pm, 32));

            const bool grow = pm > m[mt] + 8.f;     // defer-max THR=8
            const float mnew = grow ? pm : m[mt];
            al[mt] = grow ? __expf(m[mt] - mnew) : 1.f;
            const bool anyg = __any(grow);
            m[mt] = mnew;

            u32 pk[4][2];
#pragma unroll
            for (int ct = 0; ct < 4; ++ct) {
                const float p0 = __expf(sc[mt][ct][0] - mnew);
                const float p1 = __expf(sc[mt][ct][1] - mnew);
                const float p2 = __expf(sc[mt][ct][2] - mnew);
                const float p3 = __expf(sc[mt][ct][3] - mnew);
                pk[ct][0] = __builtin_bit_cast(u32, __builtin_amdgcn_cvt_pkrtz(p0, p1));
                pk[ct][1] = __builtin_bit_cast(u32, __builtin_amdgcn_cvt_pkrtz(p2, p3));
            }
            // butterfly: swap(lane-b5, pair) via shfl+sel, swap(lane-b4, pair)
            // via permlane16_swap.  pa[mt][kk] elem j = P[q][kk*32+lhi*8+j]
#pragma unroll
            for (int kk = 0; kk < 2; ++kk)
#pragma unroll
                for (int p = 0; p < 2; ++p) {
                    const u32 X = pk[2 * kk + 0][p];
                    const u32 Y = pk[2 * kk + 1][p];
                    const u32 sx = __shfl_xor(X, 32);
                    const u32 sy = __shfl_xor(Y, 32);
                    const u32 X1 = l5 ? sy : X;
                    const u32 Y1 = l5 ? Y : sx;
                    const auto u2 = __builtin_amdgcn_permlane16_swap(X1, Y1, false, false);
                    pa[mt][kk].d[p]     = u2[0];
                    pa[mt][kk].d[2 + p] = u2[1];
                }

            if (anyg) {
#pragma unroll
                for (int dt = 0; dt < 8; ++dt)
#pragma unroll
                    for (int r = 0; r < 4; ++r)
                        o[mt][dt][r] *= al[mt];
                lsum[mt] *= al[mt];
            }
        }

        // ---- PV (vf shared across m-tiles) + row-sum via ones-MFMA ----
        f32x4 lacc[2];
        lacc[0] = (f32x4){0.f, 0.f, 0.f, 0.f};
        lacc[1] = (f32x4){0.f, 0.f, 0.f, 0.f};
        __builtin_amdgcn_s_setprio(1);
#pragma unroll
        for (int kk = 0; kk < 2; ++kk) {
            lacc[0] = __builtin_amdgcn_mfma_f32_16x16x32_f16(ones, pa[0][kk].v, lacc[0], 0, 0, 0);
            lacc[1] = __builtin_amdgcn_mfma_f32_16x16x32_f16(ones, pa[1][kk].v, lacc[1], 0, 0, 0);
#pragma unroll
            for (int dt = 0; dt < 8; ++dt) {
                const f16x8 vf =
                    *(const f16x8*)(vp + (size_t)(dt * 16) * TOKENS + t0 + kk * 32);
                o[0][dt] = __builtin_amdgcn_mfma_f32_16x16x32_f16(vf, pa[0][kk].v, o[0][dt], 0, 0, 0);
                o[1][dt] = __builtin_amdgcn_mfma_f32_16x16x32_f16(vf, pa[1][kk].v, o[1][dt], 0, 0, 0);
            }
        }
        __builtin_amdgcn_s_setprio(0);
        lsum[0] += lacc[0][0];
        lsum[1] += lacc[1][0];
    }

    // ---- epilogue: O^T regs -> O[token][feature], 8B packed stores ----
#pragma unroll
    for (int mt = 0; mt < 2; ++mt) {
        const float inv = 1.f / lsum[mt];
        const size_t base = (bseq + q0 + mt * 16 + lr) * DIM + (size_t)h * HD + lhi * 4;
#pragma unroll
        for (int dt = 0; dt < 8; ++dt) {
            ushort4 h4;
            h4.x = f2h(o[mt][dt][0] * inv);
            h4.y = f2h(o[mt][dt][1] * inv);
            h4.z = f2h(o[mt][dt][2] * inv);
            h4.w = f2h(o[mt][dt][3] * inv);
            *(ushort4*)&Oh[base + dt * 16] = h4;
        }
    }
}

// ---------------------------------------------------------------------------
extern "C" void kernel_launch(void* const* d_in, const int* in_sizes, int n_in,
                              void* d_out, int out_size, void* d_ws, size_t ws_size,
                              hipStream_t stream) {
    const float* x  = (const float*)d_in[0];
    const float* wq = (const float*)d_in[1];
    const float* bq = (const float*)d_in[2];
    const float* wk = (const float*)d_in[3];
    const float* bk = (const float*)d_in[4];
    const float* wv = (const float*)d_in[5];
    const float* bv = (const float*)d_in[6];
    const float* wo = (const float*)d_in[7];
    const float* bo = (const float*)d_in[8];
    float* out = (float*)d_out;

    char* w = (char*)d_ws;
    u16* xh     = (u16*)w;                 w += (size_t)TOKENS * DIM * 2;
    u16* wcat   = (u16*)w;                 w += (size_t)NQKV * DIM * 2;
    u16* woT    = (u16*)w;                 w += (size_t)DIM * DIM * 2;
    u16* qb     = (u16*)w;                 w += (size_t)TOKENS * DIM * 2;
    u16* kb     = (u16*)w;                 w += (size_t)TOKENS * HD * 2;
    u16* vtb    = (u16*)w;                 w += (size_t)TOKENS * HD * 2;
    float* bc   = (float*)w;               w += 16384;
    u16* Oh = xh;   // x dead after QKV GEMM; stream order makes this safe

    const float scale = 0.08838834764831845f;  // 1/sqrt(128)
    const dim3 blk(256);

    conv_f16<<<TOKENS * DIM / 4 / 256, blk, 0, stream>>>(x, xh);
    transpose_f16<<<dim3(DIM / 32, DIM / 32), blk, 0, stream>>>(wq, wcat, DIM, DIM, 0);
    transpose_f16<<<dim3(DIM / 32, HD / 32), blk, 0, stream>>>(wk, wcat, DIM, HD, DIM);
    transpose_f16<<<dim3(DIM / 32, HD / 32), blk, 0, stream>>>(wv, wcat, DIM, HD, DIM + HD);
    transpose_f16<<<dim3(DIM / 32, DIM / 32), blk, 0, stream>>>(wo, woT, DIM, DIM, 0);
    concat_bias<<<NQKV / 256, blk, 0, stream>>>(bq, bk, bv, bc);

    gemm_f16<0><<<dim3(NQKV / 128, TOKENS / 128), blk, 0, stream>>>(
        xh, wcat, bc, nullptr, qb, kb, vtb, scale);

    mqa_attn_f16<<<dim3(SEQ / 128, NH, BATCH), blk, 0, stream>>>(qb, kb, vtb, Oh);

    gemm_f16<1><<<dim3(DIM / 128, TOKENS / 128), blk, 0, stream>>>(
        Oh, woT, bo, out, nullptr, nullptr, nullptr, 1.0f);
}

// Round 16
// 218.543 us; speedup vs baseline: 1.8295x; 1.8295x over previous
//
#include <hip/hip_runtime.h>
#include <hip/hip_bf16.h>
#include <math.h>

#define DIM 2048
#define NH 16
#define HD 128
#define BATCH 2
#define SEQ 2048
#define TOKENS (BATCH * SEQ)   // 4096
#define NQKV (DIM + 2 * HD)    // 2304

typedef __attribute__((ext_vector_type(8))) _Float16 f16x8;
typedef __attribute__((ext_vector_type(4))) float f32x4;
typedef unsigned short u16;
typedef unsigned int u32;

typedef union { u32 d[4]; f16x8 v; } frag_u;

__device__ __forceinline__ u16 f2h(float f) {
    union { _Float16 h; u16 u; } v; v.h = (_Float16)f; return v.u;
}
__device__ __forceinline__ void gll16(const void* g, void* l) {
    __builtin_amdgcn_global_load_lds(
        (const __attribute__((address_space(1))) unsigned int*)g,
        (__attribute__((address_space(3))) unsigned int*)l, 16, 0, 0);
}

// Attention K/V LDS swizzles (r10-verified)
#define KIDX(r, c) ((r) * 128 + (((((c) << 1)) ^ (((r) & 7) << 4)) >> 1))
#define VIDX(d, c) ((d) * 64  + (((((c) << 1)) ^ (((d) & 7) << 4)) >> 1))

// ---------------------------------------------------------------------------
// prep kernels (unchanged)
// ---------------------------------------------------------------------------
__global__ __launch_bounds__(256) void conv_f16(
    const float* __restrict__ in, u16* __restrict__ out)
{
    const int i = blockIdx.x * 256 + threadIdx.x;
    const float4 v = ((const float4*)in)[i];
    ushort4 h;
    h.x = f2h(v.x); h.y = f2h(v.y); h.z = f2h(v.z); h.w = f2h(v.w);
    ((ushort4*)out)[i] = h;
}

__global__ __launch_bounds__(256) void transpose_f16(
    const float* __restrict__ W, u16* __restrict__ T, int K, int N, int rowoff)
{
    __shared__ float tile[32][33];
    const int k0 = blockIdx.x * 32;
    const int n0 = blockIdx.y * 32;
    const int tid = threadIdx.x;
#pragma unroll
    for (int i = 0; i < 4; ++i) {
        const int idx = tid + i * 256;
        const int r = idx >> 5, c = idx & 31;
        tile[r][c] = W[(size_t)(k0 + r) * N + n0 + c];
    }
    __syncthreads();
#pragma unroll
    for (int i = 0; i < 4; ++i) {
        const int idx = tid + i * 256;
        const int r = idx >> 5, c = idx & 31;
        T[(size_t)(rowoff + n0 + r) * K + k0 + c] = f2h(tile[c][r]);
    }
}

__global__ __launch_bounds__(256) void concat_bias(
    const float* __restrict__ bq, const float* __restrict__ bk,
    const float* __restrict__ bv, float* __restrict__ bc)
{
    const int i = blockIdx.x * 256 + threadIdx.x;
    float v;
    if (i < DIM) v = bq[i];
    else if (i < DIM + HD) v = bk[i - DIM];
    else v = bv[i - DIM - HD];
    bc[i] = v;
}

// ---------------------------------------------------------------------------
// fp16 GEMM: 128x128 tile, BK=64 (32 barriers instead of 64 -> halves the
// structural vmcnt-drain cost), 2-buffer LDS (64 KB), global_load_lds with
// granule swizzle (rule #21): LDS[row][g] = global[row][g ^ (row&7)],
// read granule g' = (kk*4+lhi) ^ (row&7) -> 2 lanes/bank (free, m136).
// XCD-aware block swizzle (T1, m157; both grids %8==0 so bijective):
// each XCD owns a contiguous chunk of M-rows -> A-panels L2-resident.
// ---------------------------------------------------------------------------
template <int MODE>
__global__ __launch_bounds__(256) void gemm_f16(
    const u16* __restrict__ A, const u16* __restrict__ B,
    const float* __restrict__ bias, float* __restrict__ Cf,
    u16* __restrict__ qdst, u16* __restrict__ kdst, u16* __restrict__ vtdst,
    float scale)
{
    constexpr int BK = 64;
    constexpr int BUFE = 2 * 128 * BK;     // A|B, u16 elems (32 KB)
    __shared__ u16 lds[2][BUFE];           // 64 KB

    const int tid = threadIdx.x;
    const int wid = tid >> 6;
    const int lane = tid & 63;
    const int lr = lane & 15;
    const int lhi = lane >> 4;
    const int wr = wid >> 1, wc = wid & 1;

    // T1 XCD swizzle: flat id f runs on XCD f%8; give XCD x the contiguous
    // chunk [x*cpx, (x+1)*cpx) of the row-major (by,bx) space.
    const int nx = gridDim.x;
    const int nwg = nx * gridDim.y;
    const int flat = blockIdx.y * nx + blockIdx.x;
    const int cpx = nwg >> 3;
    const int newid = (flat & 7) * cpx + (flat >> 3);
    const int bm = (newid / nx) * 128;
    const int bn = (newid % nx) * 128;

    f32x4 acc[4][4];
#pragma unroll
    for (int i = 0; i < 4; ++i)
#pragma unroll
        for (int j = 0; j < 4; ++j) acc[i][j] = (f32x4){0.f, 0.f, 0.f, 0.f};

    // 1024 granules (16B) per matrix per tile; 256 thr -> 4 A + 4 B each.
#define STAGE(buf_, k0_)                                                      \
    {                                                                         \
        _Pragma("unroll")                                                     \
        for (int i = 0; i < 4; ++i) {                                         \
            const int slot = i * 256 + tid;                                   \
            const int row = slot >> 3;                                        \
            const int gsrc = ((slot & 7) ^ (row & 7)) * 8;                    \
            char* lbase = (char*)lds[buf_] + (size_t)(i * 256 + wid * 64) * 16; \
            gll16(A + (size_t)(bm + row) * DIM + (k0_) + gsrc, lbase);        \
            gll16(B + (size_t)(bn + row) * DIM + (k0_) + gsrc, lbase + 16384);\
        }                                                                     \
    }

    STAGE(0, 0);
    __syncthreads();

    int cur = 0;
    for (int k0 = 0; k0 < DIM; k0 += BK) {
        if (k0 + BK < DIM) STAGE(cur ^ 1, k0 + BK);   // prefetch under compute

        __builtin_amdgcn_s_setprio(1);
#pragma unroll
        for (int kk = 0; kk < 2; ++kk) {
            f16x8 a[4], b[4];
#pragma unroll
            for (int i = 0; i < 4; ++i) {
                const int mrow = wr * 64 + i * 16 + lr;
                const int nrow = wc * 64 + i * 16 + lr;
                const int ga = ((kk * 4 + lhi) ^ (mrow & 7)) * 8;
                const int gb = ((kk * 4 + lhi) ^ (nrow & 7)) * 8;
                a[i] = *(const f16x8*)&lds[cur][mrow * BK + ga];
                b[i] = *(const f16x8*)&lds[cur][8192 + nrow * BK + gb];
            }
#pragma unroll
            for (int i = 0; i < 4; ++i)
#pragma unroll
                for (int j = 0; j < 4; ++j)
                    acc[i][j] = __builtin_amdgcn_mfma_f32_16x16x32_f16(a[i], b[j], acc[i][j], 0, 0, 0);
        }
        __builtin_amdgcn_s_setprio(0);
        __syncthreads();
        cur ^= 1;
    }
#undef STAGE

    const float alpha = (MODE == 0 && bn < DIM) ? scale : 1.0f;
    float bj[4];
#pragma unroll
    for (int j = 0; j < 4; ++j) bj[j] = bias[bn + wc * 64 + j * 16 + lr];

#pragma unroll
    for (int i = 0; i < 4; ++i) {
#pragma unroll
        for (int j = 0; j < 4; ++j) {
#pragma unroll
            for (int r = 0; r < 4; ++r) {
                const int row = bm + wr * 64 + i * 16 + lhi * 4 + r;
                const int col = bn + wc * 64 + j * 16 + lr;
                const float val = (acc[i][j][r] + bj[j]) * alpha;
                if (MODE == 1) {
                    Cf[(size_t)row * DIM + col] = val;
                } else if (bn < DIM) {
                    qdst[(size_t)row * DIM + col] = f2h(val);
                } else if (bn < DIM + HD) {
                    kdst[(size_t)row * HD + (col - DIM)] = f2h(val);
                } else {
                    vtdst[(size_t)(col - DIM - HD) * TOKENS + row] = f2h(val);
                }
            }
        }
    }
}

// ---------------------------------------------------------------------------
// MQA flash attention (r10 verbatim — best measured: 102.6 us):
// swapped-operand QK^T (T12) + one-tile-delayed PV (T15, tri-buffered V).
// ---------------------------------------------------------------------------
__global__ __launch_bounds__(256, 2) void mqa_attn_f16(
    const u16* __restrict__ Q, const u16* __restrict__ Kg,
    const u16* __restrict__ Vtg, u16* __restrict__ Oh)
{
    __shared__ __align__(16) u16 Ks[2][64 * 128];   // 32 KB
    __shared__ __align__(16) u16 Vt[3][128 * 64];   // 48 KB (tri-buffer)

    const int tid = threadIdx.x;
    const int wid = tid >> 6;
    const int lane = tid & 63;
    const int lr = lane & 15;
    const int lhi = lane >> 4;
    const bool l5 = (lhi & 2) != 0;   // lane bit 5

    const int qt = blockIdx.x;
    const int h  = blockIdx.y;
    const int b  = blockIdx.z;
    const size_t bseq = (size_t)b * SEQ;
    const int q0 = qt * 128 + wid * 32;

    f16x8 qf[2][4];
#pragma unroll
    for (int mt = 0; mt < 2; ++mt) {
        const u16* qrow = Q + (bseq + q0 + mt * 16 + lr) * DIM + (size_t)h * HD;
#pragma unroll
        for (int kk = 0; kk < 4; ++kk)
            qf[mt][kk] = *(const f16x8*)(qrow + kk * 32 + lhi * 8);
    }

    f16x8 ones;
#pragma unroll
    for (int j = 0; j < 8; ++j) ones[j] = (_Float16)1.0f;

    f32x4 o[2][8];
#pragma unroll
    for (int mt = 0; mt < 2; ++mt)
#pragma unroll
        for (int dt = 0; dt < 8; ++dt) o[mt][dt] = (f32x4){0.f, 0.f, 0.f, 0.f};
    float m[2]    = {-INFINITY, -INFINITY};
    float lsum[2] = {0.f, 0.f};

    frag_u pa[2][2];
#pragma unroll
    for (int mt = 0; mt < 2; ++mt)
#pragma unroll
        for (int kk = 0; kk < 2; ++kk)
#pragma unroll
            for (int p = 0; p < 4; ++p) pa[mt][kk].d[p] = 0u;

#define STAGE_K(buf_, t0_)                                                    \
    {                                                                         \
        _Pragma("unroll")                                                     \
        for (int i = 0; i < 4; ++i) {                                         \
            const int L = i * 256 + tid;                                      \
            char* kbase = (char*)&Ks[buf_][0] + (size_t)(i * 256 + wid * 64) * 16; \
            const int krow = L >> 4, kc = (L & 15) ^ ((L >> 4) & 7);          \
            gll16(&Kg[(bseq + (t0_) + krow) * HD + kc * 8], kbase);           \
        }                                                                     \
    }
#define STAGE_V(buf_, t0_)                                                    \
    {                                                                         \
        _Pragma("unroll")                                                     \
        for (int i = 0; i < 4; ++i) {                                         \
            const int L = i * 256 + tid;                                      \
            char* vbase = (char*)&Vt[buf_][0] + (size_t)(i * 256 + wid * 64) * 16; \
            const int vrow = L >> 3, vc = (L & 7) ^ ((L >> 3) & 7);           \
            gll16(&Vtg[(size_t)vrow * TOKENS + bseq + (t0_) + vc * 8], vbase);\
        }                                                                     \
    }

    STAGE_K(0, 0);
    STAGE_V(0, 0);
    __syncthreads();

    int kcur = 0;
    int vprev = 0, vcur = 0, vnxt = 1;   // PV_{-1} reads Vt[0] (valid data)

    for (int t0 = 0; t0 < SEQ; t0 += 64) {
        if (t0 + 64 < SEQ) {
            STAGE_K(kcur ^ 1, t0 + 64);
            STAGE_V(vnxt, t0 + 64);
        }

        // ---- QK_t (swapped): sc[mt][ct] = S^T[kv=ct*16+lhi*4+r][q] ----
        f32x4 sc[2][4];
#pragma unroll
        for (int mt = 0; mt < 2; ++mt)
#pragma unroll
            for (int ct = 0; ct < 4; ++ct) sc[mt][ct] = (f32x4){0.f, 0.f, 0.f, 0.f};
        __builtin_amdgcn_s_setprio(1);
#pragma unroll
        for (int kk = 0; kk < 4; ++kk)
#pragma unroll
            for (int ct = 0; ct < 4; ++ct) {
                const f16x8 kf = *(const f16x8*)&Ks[kcur][KIDX(ct * 16 + lr, kk * 32 + lhi * 8)];
                sc[0][ct] = __builtin_amdgcn_mfma_f32_16x16x32_f16(kf, qf[0][kk], sc[0][ct], 0, 0, 0);
                sc[1][ct] = __builtin_amdgcn_mfma_f32_16x16x32_f16(kf, qf[1][kk], sc[1][ct], 0, 0, 0);
            }
        __builtin_amdgcn_s_setprio(0);

        // ---- PV_{t-1} (MFMA chain, independent of softmax_t below) ----
        f32x4 lacc[2];
        lacc[0] = (f32x4){0.f, 0.f, 0.f, 0.f};
        lacc[1] = (f32x4){0.f, 0.f, 0.f, 0.f};
        __builtin_amdgcn_s_setprio(1);
#pragma unroll
        for (int kk = 0; kk < 2; ++kk) {
            lacc[0] = __builtin_amdgcn_mfma_f32_16x16x32_f16(ones, pa[0][kk].v, lacc[0], 0, 0, 0);
            lacc[1] = __builtin_amdgcn_mfma_f32_16x16x32_f16(ones, pa[1][kk].v, lacc[1], 0, 0, 0);
#pragma unroll
            for (int dt = 0; dt < 8; ++dt) {
                const f16x8 vf = *(const f16x8*)&Vt[vprev][VIDX(dt * 16 + lr, kk * 32 + lhi * 8)];
                o[0][dt] = __builtin_amdgcn_mfma_f32_16x16x32_f16(vf, pa[0][kk].v, o[0][dt], 0, 0, 0);
                o[1][dt] = __builtin_amdgcn_mfma_f32_16x16x32_f16(vf, pa[1][kk].v, o[1][dt], 0, 0, 0);
            }
        }
        __builtin_amdgcn_s_setprio(0);

        // ---- softmax_t (VALU chain; overlaps PV) ----
        frag_u panew[2][2];
        float mnew[2];
        bool grow[2];
#pragma unroll
        for (int mt = 0; mt < 2; ++mt) {
            float pm = fmaxf(fmaxf(fmaxf(sc[mt][0][0], sc[mt][0][1]),
                                   fmaxf(sc[mt][0][2], sc[mt][0][3])),
                             fmaxf(fmaxf(sc[mt][1][0], sc[mt][1][1]),
                                   fmaxf(sc[mt][1][2], sc[mt][1][3])));
            pm = fmaxf(pm, fmaxf(fmaxf(fmaxf(sc[mt][2][0], sc[mt][2][1]),
                                       fmaxf(sc[mt][2][2], sc[mt][2][3])),
                                 fmaxf(fmaxf(sc[mt][3][0], sc[mt][3][1]),
                                       fmaxf(sc[mt][3][2], sc[mt][3][3]))));
            pm = fmaxf(pm, __shfl_xor(pm, 16));
            pm = fmaxf(pm, __shfl_xor(pm, 32));

            grow[mt] = pm > m[mt] + 8.f;          // defer-max THR=8
            mnew[mt] = grow[mt] ? pm : m[mt];

            u32 pk[4][2];
#pragma unroll
            for (int ct = 0; ct < 4; ++ct) {
                const float p0 = __expf(sc[mt][ct][0] - mnew[mt]);
                const float p1 = __expf(sc[mt][ct][1] - mnew[mt]);
                const float p2 = __expf(sc[mt][ct][2] - mnew[mt]);
                const float p3 = __expf(sc[mt][ct][3] - mnew[mt]);
                pk[ct][0] = __builtin_bit_cast(u32, __builtin_amdgcn_cvt_pkrtz(p0, p1));
                pk[ct][1] = __builtin_bit_cast(u32, __builtin_amdgcn_cvt_pkrtz(p2, p3));
            }
#pragma unroll
            for (int kk = 0; kk < 2; ++kk)
#pragma unroll
                for (int p = 0; p < 2; ++p) {
                    const u32 X = pk[2 * kk + 0][p];
                    const u32 Y = pk[2 * kk + 1][p];
                    const u32 sx = __shfl_xor(X, 32);
                    const u32 sy = __shfl_xor(Y, 32);
                    const u32 X1 = l5 ? sy : X;
                    const u32 Y1 = l5 ? Y : sx;
                    const auto u2 = __builtin_amdgcn_permlane16_swap(X1, Y1, false, false);
                    panew[mt][kk].d[p]     = u2[0];
                    panew[mt][kk].d[2 + p] = u2[1];
                }
        }

        // ---- dependent tail: fold lacc, rescale, commit state ----
#pragma unroll
        for (int mt = 0; mt < 2; ++mt) {
            lsum[mt] += lacc[mt][0];
            if (__any(grow[mt])) {
                const float al = grow[mt] ? __expf(m[mt] - mnew[mt]) : 1.f;
#pragma unroll
                for (int dt = 0; dt < 8; ++dt)
#pragma unroll
                    for (int r = 0; r < 4; ++r)
                        o[mt][dt][r] *= al;
                lsum[mt] *= al;
            }
            m[mt] = mnew[mt];
#pragma unroll
            for (int kk = 0; kk < 2; ++kk)
                pa[mt][kk] = panew[mt][kk];
        }

        __syncthreads();   // drains prefetch vmcnt; releases read buffers
        kcur ^= 1;
        vprev = vcur; vcur = vnxt; vnxt = (vnxt + 1 == 3) ? 0 : vnxt + 1;
    }
#undef STAGE_K
#undef STAGE_V

    // ---- final PV (tile NT-1) ----
    {
        f32x4 lacc[2];
        lacc[0] = (f32x4){0.f, 0.f, 0.f, 0.f};
        lacc[1] = (f32x4){0.f, 0.f, 0.f, 0.f};
#pragma unroll
        for (int kk = 0; kk < 2; ++kk) {
            lacc[0] = __builtin_amdgcn_mfma_f32_16x16x32_f16(ones, pa[0][kk].v, lacc[0], 0, 0, 0);
            lacc[1] = __builtin_amdgcn_mfma_f32_16x16x32_f16(ones, pa[1][kk].v, lacc[1], 0, 0, 0);
#pragma unroll
            for (int dt = 0; dt < 8; ++dt) {
                const f16x8 vf = *(const f16x8*)&Vt[vprev][VIDX(dt * 16 + lr, kk * 32 + lhi * 8)];
                o[0][dt] = __builtin_amdgcn_mfma_f32_16x16x32_f16(vf, pa[0][kk].v, o[0][dt], 0, 0, 0);
                o[1][dt] = __builtin_amdgcn_mfma_f32_16x16x32_f16(vf, pa[1][kk].v, o[1][dt], 0, 0, 0);
            }
        }
        lsum[0] += lacc[0][0];
        lsum[1] += lacc[1][0];
    }

    // ---- epilogue: O^T regs -> O[token][feature], 8B packed stores ----
#pragma unroll
    for (int mt = 0; mt < 2; ++mt) {
        const float inv = 1.f / lsum[mt];
        const size_t base = (bseq + q0 + mt * 16 + lr) * DIM + (size_t)h * HD + lhi * 4;
#pragma unroll
        for (int dt = 0; dt < 8; ++dt) {
            ushort4 h4;
            h4.x = f2h(o[mt][dt][0] * inv);
            h4.y = f2h(o[mt][dt][1] * inv);
            h4.z = f2h(o[mt][dt][2] * inv);
            h4.w = f2h(o[mt][dt][3] * inv);
            *(ushort4*)&Oh[base + dt * 16] = h4;
        }
    }
}

// ---------------------------------------------------------------------------
extern "C" void kernel_launch(void* const* d_in, const int* in_sizes, int n_in,
                              void* d_out, int out_size, void* d_ws, size_t ws_size,
                              hipStream_t stream) {
    const float* x  = (const float*)d_in[0];
    const float* wq = (const float*)d_in[1];
    const float* bq = (const float*)d_in[2];
    const float* wk = (const float*)d_in[3];
    const float* bk = (const float*)d_in[4];
    const float* wv = (const float*)d_in[5];
    const float* bv = (const float*)d_in[6];
    const float* wo = (const float*)d_in[7];
    const float* bo = (const float*)d_in[8];
    float* out = (float*)d_out;

    char* w = (char*)d_ws;
    u16* xh     = (u16*)w;                 w += (size_t)TOKENS * DIM * 2;
    u16* wcat   = (u16*)w;                 w += (size_t)NQKV * DIM * 2;
    u16* woT    = (u16*)w;                 w += (size_t)DIM * DIM * 2;
    u16* qb     = (u16*)w;                 w += (size_t)TOKENS * DIM * 2;
    u16* kb     = (u16*)w;                 w += (size_t)TOKENS * HD * 2;
    u16* vtb    = (u16*)w;                 w += (size_t)TOKENS * HD * 2;
    float* bc   = (float*)w;               w += 16384;
    u16* Oh = xh;   // x dead after QKV GEMM; stream order makes this safe

    const float scale = 0.08838834764831845f;  // 1/sqrt(128)
    const dim3 blk(256);

    conv_f16<<<TOKENS * DIM / 4 / 256, blk, 0, stream>>>(x, xh);
    transpose_f16<<<dim3(DIM / 32, DIM / 32), blk, 0, stream>>>(wq, wcat, DIM, DIM, 0);
    transpose_f16<<<dim3(DIM / 32, HD / 32), blk, 0, stream>>>(wk, wcat, DIM, HD, DIM);
    transpose_f16<<<dim3(DIM / 32, HD / 32), blk, 0, stream>>>(wv, wcat, DIM, HD, DIM + HD);
    transpose_f16<<<dim3(DIM / 32, DIM / 32), blk, 0, stream>>>(wo, woT, DIM, DIM, 0);
    concat_bias<<<NQKV / 256, blk, 0, stream>>>(bq, bk, bv, bc);

    gemm_f16<0><<<dim3(NQKV / 128, TOKENS / 128), blk, 0, stream>>>(
        xh, wcat, bc, nullptr, qb, kb, vtb, scale);

    mqa_attn_f16<<<dim3(SEQ / 128, NH, BATCH), blk, 0, stream>>>(qb, kb, vtb, Oh);

    gemm_f16<1><<<dim3(DIM / 128, TOKENS / 128), blk, 0, stream>>>(
        Oh, woT, bo, out, nullptr, nullptr, nullptr, 1.0f);
}

// Round 18
// 217.586 us; speedup vs baseline: 1.8376x; 1.0044x over previous
//
#include <hip/hip_runtime.h>
#include <hip/hip_bf16.h>
#include <math.h>

#define DIM 2048
#define NH 16
#define HD 128
#define BATCH 2
#define SEQ 2048
#define TOKENS (BATCH * SEQ)   // 4096
#define NQKV (DIM + 2 * HD)    // 2304

typedef __attribute__((ext_vector_type(8))) _Float16 f16x8;
typedef __attribute__((ext_vector_type(4))) float f32x4;
typedef unsigned short u16;
typedef unsigned int u32;

typedef union { u32 d[4]; f16x8 v; } frag_u;

__device__ __forceinline__ u16 f2h(float f) {
    union { _Float16 h; u16 u; } v; v.h = (_Float16)f; return v.u;
}
__device__ __forceinline__ void gll16(const void* g, void* l) {
    __builtin_amdgcn_global_load_lds(
        (const __attribute__((address_space(1))) unsigned int*)g,
        (__attribute__((address_space(3))) unsigned int*)l, 16, 0, 0);
}

// ---------------------------------------------------------------------------
// prep kernels (unchanged)
// ---------------------------------------------------------------------------
__global__ __launch_bounds__(256) void conv_f16(
    const float* __restrict__ in, u16* __restrict__ out)
{
    const int i = blockIdx.x * 256 + threadIdx.x;
    const float4 v = ((const float4*)in)[i];
    ushort4 h;
    h.x = f2h(v.x); h.y = f2h(v.y); h.z = f2h(v.z); h.w = f2h(v.w);
    ((ushort4*)out)[i] = h;
}

__global__ __launch_bounds__(256) void transpose_f16(
    const float* __restrict__ W, u16* __restrict__ T, int K, int N, int rowoff)
{
    __shared__ float tile[32][33];
    const int k0 = blockIdx.x * 32;
    const int n0 = blockIdx.y * 32;
    const int tid = threadIdx.x;
#pragma unroll
    for (int i = 0; i < 4; ++i) {
        const int idx = tid + i * 256;
        const int r = idx >> 5, c = idx & 31;
        tile[r][c] = W[(size_t)(k0 + r) * N + n0 + c];
    }
    __syncthreads();
#pragma unroll
    for (int i = 0; i < 4; ++i) {
        const int idx = tid + i * 256;
        const int r = idx >> 5, c = idx & 31;
        T[(size_t)(rowoff + n0 + r) * K + k0 + c] = f2h(tile[c][r]);
    }
}

__global__ __launch_bounds__(256) void concat_bias(
    const float* __restrict__ bq, const float* __restrict__ bk,
    const float* __restrict__ bv, float* __restrict__ bc)
{
    const int i = blockIdx.x * 256 + threadIdx.x;
    float v;
    if (i < DIM) v = bq[i];
    else if (i < DIM + HD) v = bk[i - DIM];
    else v = bv[i - DIM - HD];
    bc[i] = v;
}

// ---------------------------------------------------------------------------
// fp16 GEMM (r16 verbatim): 128x128 tile, BK=64, 2-buffer LDS, granule
// swizzle, T1 XCD block swizzle.
// ---------------------------------------------------------------------------
template <int MODE>
__global__ __launch_bounds__(256) void gemm_f16(
    const u16* __restrict__ A, const u16* __restrict__ B,
    const float* __restrict__ bias, float* __restrict__ Cf,
    u16* __restrict__ qdst, u16* __restrict__ kdst, u16* __restrict__ vtdst,
    float scale)
{
    constexpr int BK = 64;
    constexpr int BUFE = 2 * 128 * BK;
    __shared__ u16 lds[2][BUFE];

    const int tid = threadIdx.x;
    const int wid = tid >> 6;
    const int lane = tid & 63;
    const int lr = lane & 15;
    const int lhi = lane >> 4;
    const int wr = wid >> 1, wc = wid & 1;

    const int nx = gridDim.x;
    const int nwg = nx * gridDim.y;
    const int flat = blockIdx.y * nx + blockIdx.x;
    const int cpx = nwg >> 3;
    const int newid = (flat & 7) * cpx + (flat >> 3);
    const int bm = (newid / nx) * 128;
    const int bn = (newid % nx) * 128;

    f32x4 acc[4][4];
#pragma unroll
    for (int i = 0; i < 4; ++i)
#pragma unroll
        for (int j = 0; j < 4; ++j) acc[i][j] = (f32x4){0.f, 0.f, 0.f, 0.f};

#define STAGE(buf_, k0_)                                                      \
    {                                                                         \
        _Pragma("unroll")                                                     \
        for (int i = 0; i < 4; ++i) {                                         \
            const int slot = i * 256 + tid;                                   \
            const int row = slot >> 3;                                        \
            const int gsrc = ((slot & 7) ^ (row & 7)) * 8;                    \
            char* lbase = (char*)lds[buf_] + (size_t)(i * 256 + wid * 64) * 16; \
            gll16(A + (size_t)(bm + row) * DIM + (k0_) + gsrc, lbase);        \
            gll16(B + (size_t)(bn + row) * DIM + (k0_) + gsrc, lbase + 16384);\
        }                                                                     \
    }

    STAGE(0, 0);
    __syncthreads();

    int cur = 0;
    for (int k0 = 0; k0 < DIM; k0 += BK) {
        if (k0 + BK < DIM) STAGE(cur ^ 1, k0 + BK);

        __builtin_amdgcn_s_setprio(1);
#pragma unroll
        for (int kk = 0; kk < 2; ++kk) {
            f16x8 a[4], b[4];
#pragma unroll
            for (int i = 0; i < 4; ++i) {
                const int mrow = wr * 64 + i * 16 + lr;
                const int nrow = wc * 64 + i * 16 + lr;
                const int ga = ((kk * 4 + lhi) ^ (mrow & 7)) * 8;
                const int gb = ((kk * 4 + lhi) ^ (nrow & 7)) * 8;
                a[i] = *(const f16x8*)&lds[cur][mrow * BK + ga];
                b[i] = *(const f16x8*)&lds[cur][8192 + nrow * BK + gb];
            }
#pragma unroll
            for (int i = 0; i < 4; ++i)
#pragma unroll
                for (int j = 0; j < 4; ++j)
                    acc[i][j] = __builtin_amdgcn_mfma_f32_16x16x32_f16(a[i], b[j], acc[i][j], 0, 0, 0);
        }
        __builtin_amdgcn_s_setprio(0);
        __syncthreads();
        cur ^= 1;
    }
#undef STAGE

    const float alpha = (MODE == 0 && bn < DIM) ? scale : 1.0f;
    float bj[4];
#pragma unroll
    for (int j = 0; j < 4; ++j) bj[j] = bias[bn + wc * 64 + j * 16 + lr];

#pragma unroll
    for (int i = 0; i < 4; ++i) {
#pragma unroll
        for (int j = 0; j < 4; ++j) {
#pragma unroll
            for (int r = 0; r < 4; ++r) {
                const int row = bm + wr * 64 + i * 16 + lhi * 4 + r;
                const int col = bn + wc * 64 + j * 16 + lr;
                const float val = (acc[i][j][r] + bj[j]) * alpha;
                if (MODE == 1) {
                    Cf[(size_t)row * DIM + col] = val;
                } else if (bn < DIM) {
                    qdst[(size_t)row * DIM + col] = f2h(val);
                } else if (bn < DIM + HD) {
                    kdst[(size_t)row * HD + (col - DIM)] = f2h(val);
                } else {
                    vtdst[(size_t)(col - DIM - HD) * TOKENS + row] = f2h(val);
                }
            }
        }
    }
}

// ---------------------------------------------------------------------------
// MQA flash attention (r10 structure + hoisted addressing, V-stage FIXED):
// K tile 64x128 u16 (16 granules/row, XOR (row&7)); V tile 128x64 u16
// (8 granules/row, XOR (row&7)).  Hoisted:
//   K: krow = i*16 + (tid>>4); (krow&7)=(tid>>4)&7 -> kc0 const; stride 16*HD
//   V: vrow = i*32 + (tid>>3); (vrow&7)=(tid>>3)&7 -> vg0 const; stride 32*TOKENS
// Fragment reads: base koff[kk]/voff[kk] + compile-time ct/dt offsets.
// Math bit-identical to r10/r16.
// ---------------------------------------------------------------------------
__global__ __launch_bounds__(256, 2) void mqa_attn_f16(
    const u16* __restrict__ Q, const u16* __restrict__ Kg,
    const u16* __restrict__ Vtg, u16* __restrict__ Oh)
{
    __shared__ __align__(16) u16 Ks[2][64 * 128];   // 32 KB
    __shared__ __align__(16) u16 Vt[3][128 * 64];   // 48 KB (tri-buffer)

    const int tid = threadIdx.x;
    const int wid = tid >> 6;
    const int lane = tid & 63;
    const int lr = lane & 15;
    const int lhi = lane >> 4;
    const bool l5 = (lhi & 2) != 0;

    const int qt = blockIdx.x;
    const int h  = blockIdx.y;
    const int b  = blockIdx.z;
    const size_t bseq = (size_t)b * SEQ;
    const int q0 = qt * 128 + wid * 32;

    f16x8 qf[2][4];
#pragma unroll
    for (int mt = 0; mt < 2; ++mt) {
        const u16* qrow = Q + (bseq + q0 + mt * 16 + lr) * DIM + (size_t)h * HD;
#pragma unroll
        for (int kk = 0; kk < 4; ++kk)
            qf[mt][kk] = *(const f16x8*)(qrow + kk * 32 + lhi * 8);
    }

    f16x8 ones;
#pragma unroll
    for (int j = 0; j < 8; ++j) ones[j] = (_Float16)1.0f;

    f32x4 o[2][8];
#pragma unroll
    for (int mt = 0; mt < 2; ++mt)
#pragma unroll
        for (int dt = 0; dt < 8; ++dt) o[mt][dt] = (f32x4){0.f, 0.f, 0.f, 0.f};
    float m[2]    = {-INFINITY, -INFINITY};
    float lsum[2] = {0.f, 0.f};

    frag_u pa[2][2];
#pragma unroll
    for (int mt = 0; mt < 2; ++mt)
#pragma unroll
        for (int kk = 0; kk < 2; ++kk)
#pragma unroll
            for (int p = 0; p < 4; ++p) pa[mt][kk].d[p] = 0u;

    // ---- hoisted stage addressing ----
    const int krow0 = tid >> 4;                    // 0..15
    const int kc0 = (tid & 15) ^ (krow0 & 7);
    const u16* kgp = Kg + (bseq + krow0) * HD + kc0 * 8;
    const int vrow0 = tid >> 3;                    // 0..31
    const int vg0 = (tid & 7) ^ (vrow0 & 7);
    const u16* vgp = Vtg + (size_t)vrow0 * TOKENS + bseq + vg0 * 8;

#define STAGE_K(buf_)                                                         \
    {                                                                         \
        _Pragma("unroll")                                                     \
        for (int i = 0; i < 4; ++i) {                                         \
            char* kbase = (char*)&Ks[buf_][0] + (size_t)(i * 256 + wid * 64) * 16; \
            gll16(kgp + (size_t)i * (16 * HD), kbase);                        \
        }                                                                     \
    }
#define STAGE_V(buf_)                                                         \
    {                                                                         \
        _Pragma("unroll")                                                     \
        for (int i = 0; i < 4; ++i) {                                         \
            char* vbase = (char*)&Vt[buf_][0] + (size_t)(i * 256 + wid * 64) * 16; \
            gll16(vgp + (size_t)i * (32 * TOKENS), vbase);                    \
        }                                                                     \
    }

    // ---- hoisted fragment offsets (u16 elem index) ----
    int koff[4], voff[2];
#pragma unroll
    for (int kk = 0; kk < 4; ++kk)
        koff[kk] = lr * 128 + (((kk * 4 + lhi) ^ (lr & 7)) << 3);
#pragma unroll
    for (int kk = 0; kk < 2; ++kk)
        voff[kk] = lr * 64 + (((kk * 4 + lhi) ^ (lr & 7)) << 3);

    STAGE_K(0);
    STAGE_V(0);
    kgp += 64 * HD;
    vgp += 64;
    __syncthreads();

    int kcur = 0;
    int vprev = 0, vcur = 0, vnxt = 1;

    for (int t0 = 0; t0 < SEQ; t0 += 64) {
        if (t0 + 64 < SEQ) {
            STAGE_K(kcur ^ 1);
            STAGE_V(vnxt);
            kgp += 64 * HD;
            vgp += 64;
        }

        // ---- QK_t (swapped) ----
        f32x4 sc[2][4];
#pragma unroll
        for (int mt = 0; mt < 2; ++mt)
#pragma unroll
            for (int ct = 0; ct < 4; ++ct) sc[mt][ct] = (f32x4){0.f, 0.f, 0.f, 0.f};
        __builtin_amdgcn_s_setprio(1);
#pragma unroll
        for (int kk = 0; kk < 4; ++kk) {
            const u16* kb = &Ks[kcur][koff[kk]];
#pragma unroll
            for (int ct = 0; ct < 4; ++ct) {
                const f16x8 kf = *(const f16x8*)&kb[ct * (16 * 128)];
                sc[0][ct] = __builtin_amdgcn_mfma_f32_16x16x32_f16(kf, qf[0][kk], sc[0][ct], 0, 0, 0);
                sc[1][ct] = __builtin_amdgcn_mfma_f32_16x16x32_f16(kf, qf[1][kk], sc[1][ct], 0, 0, 0);
            }
        }
        __builtin_amdgcn_s_setprio(0);

        // ---- PV_{t-1} ----
        f32x4 lacc[2];
        lacc[0] = (f32x4){0.f, 0.f, 0.f, 0.f};
        lacc[1] = (f32x4){0.f, 0.f, 0.f, 0.f};
        __builtin_amdgcn_s_setprio(1);
#pragma unroll
        for (int kk = 0; kk < 2; ++kk) {
            const u16* vb = &Vt[vprev][voff[kk]];
            lacc[0] = __builtin_amdgcn_mfma_f32_16x16x32_f16(ones, pa[0][kk].v, lacc[0], 0, 0, 0);
            lacc[1] = __builtin_amdgcn_mfma_f32_16x16x32_f16(ones, pa[1][kk].v, lacc[1], 0, 0, 0);
#pragma unroll
            for (int dt = 0; dt < 8; ++dt) {
                const f16x8 vf = *(const f16x8*)&vb[dt * (16 * 64)];
                o[0][dt] = __builtin_amdgcn_mfma_f32_16x16x32_f16(vf, pa[0][kk].v, o[0][dt], 0, 0, 0);
                o[1][dt] = __builtin_amdgcn_mfma_f32_16x16x32_f16(vf, pa[1][kk].v, o[1][dt], 0, 0, 0);
            }
        }
        __builtin_amdgcn_s_setprio(0);

        // ---- softmax_t (overlaps PV) ----
        frag_u panew[2][2];
        float mnew[2];
        bool grow[2];
#pragma unroll
        for (int mt = 0; mt < 2; ++mt) {
            float pm = fmaxf(fmaxf(fmaxf(sc[mt][0][0], sc[mt][0][1]),
                                   fmaxf(sc[mt][0][2], sc[mt][0][3])),
                             fmaxf(fmaxf(sc[mt][1][0], sc[mt][1][1]),
                                   fmaxf(sc[mt][1][2], sc[mt][1][3])));
            pm = fmaxf(pm, fmaxf(fmaxf(fmaxf(sc[mt][2][0], sc[mt][2][1]),
                                       fmaxf(sc[mt][2][2], sc[mt][2][3])),
                                 fmaxf(fmaxf(sc[mt][3][0], sc[mt][3][1]),
                                       fmaxf(sc[mt][3][2], sc[mt][3][3]))));
            pm = fmaxf(pm, __shfl_xor(pm, 16));
            pm = fmaxf(pm, __shfl_xor(pm, 32));

            grow[mt] = pm > m[mt] + 8.f;
            mnew[mt] = grow[mt] ? pm : m[mt];

            u32 pk[4][2];
#pragma unroll
            for (int ct = 0; ct < 4; ++ct) {
                const float p0 = __expf(sc[mt][ct][0] - mnew[mt]);
                const float p1 = __expf(sc[mt][ct][1] - mnew[mt]);
                const float p2 = __expf(sc[mt][ct][2] - mnew[mt]);
                const float p3 = __expf(sc[mt][ct][3] - mnew[mt]);
                pk[ct][0] = __builtin_bit_cast(u32, __builtin_amdgcn_cvt_pkrtz(p0, p1));
                pk[ct][1] = __builtin_bit_cast(u32, __builtin_amdgcn_cvt_pkrtz(p2, p3));
            }
#pragma unroll
            for (int kk = 0; kk < 2; ++kk)
#pragma unroll
                for (int p = 0; p < 2; ++p) {
                    const u32 X = pk[2 * kk + 0][p];
                    const u32 Y = pk[2 * kk + 1][p];
                    const u32 sx = __shfl_xor(X, 32);
                    const u32 sy = __shfl_xor(Y, 32);
                    const u32 X1 = l5 ? sy : X;
                    const u32 Y1 = l5 ? Y : sx;
                    const auto u2 = __builtin_amdgcn_permlane16_swap(X1, Y1, false, false);
                    panew[mt][kk].d[p]     = u2[0];
                    panew[mt][kk].d[2 + p] = u2[1];
                }
        }

        // ---- dependent tail ----
#pragma unroll
        for (int mt = 0; mt < 2; ++mt) {
            lsum[mt] += lacc[mt][0];
            if (__any(grow[mt])) {
                const float al = grow[mt] ? __expf(m[mt] - mnew[mt]) : 1.f;
#pragma unroll
                for (int dt = 0; dt < 8; ++dt)
#pragma unroll
                    for (int r = 0; r < 4; ++r)
                        o[mt][dt][r] *= al;
                lsum[mt] *= al;
            }
            m[mt] = mnew[mt];
#pragma unroll
            for (int kk = 0; kk < 2; ++kk)
                pa[mt][kk] = panew[mt][kk];
        }

        __syncthreads();
        kcur ^= 1;
        vprev = vcur; vcur = vnxt; vnxt = (vnxt + 1 == 3) ? 0 : vnxt + 1;
    }
#undef STAGE_K
#undef STAGE_V

    // ---- final PV (tile NT-1) ----
    {
        f32x4 lacc[2];
        lacc[0] = (f32x4){0.f, 0.f, 0.f, 0.f};
        lacc[1] = (f32x4){0.f, 0.f, 0.f, 0.f};
#pragma unroll
        for (int kk = 0; kk < 2; ++kk) {
            const u16* vb = &Vt[vprev][voff[kk]];
            lacc[0] = __builtin_amdgcn_mfma_f32_16x16x32_f16(ones, pa[0][kk].v, lacc[0], 0, 0, 0);
            lacc[1] = __builtin_amdgcn_mfma_f32_16x16x32_f16(ones, pa[1][kk].v, lacc[1], 0, 0, 0);
#pragma unroll
            for (int dt = 0; dt < 8; ++dt) {
                const f16x8 vf = *(const f16x8*)&vb[dt * (16 * 64)];
                o[0][dt] = __builtin_amdgcn_mfma_f32_16x16x32_f16(vf, pa[0][kk].v, o[0][dt], 0, 0, 0);
                o[1][dt] = __builtin_amdgcn_mfma_f32_16x16x32_f16(vf, pa[1][kk].v, o[1][dt], 0, 0, 0);
            }
        }
        lsum[0] += lacc[0][0];
        lsum[1] += lacc[1][0];
    }

    // ---- epilogue ----
#pragma unroll
    for (int mt = 0; mt < 2; ++mt) {
        const float inv = 1.f / lsum[mt];
        const size_t base = (bseq + q0 + mt * 16 + lr) * DIM + (size_t)h * HD + lhi * 4;
#pragma unroll
        for (int dt = 0; dt < 8; ++dt) {
            ushort4 h4;
            h4.x = f2h(o[mt][dt][0] * inv);
            h4.y = f2h(o[mt][dt][1] * inv);
            h4.z = f2h(o[mt][dt][2] * inv);
            h4.w = f2h(o[mt][dt][3] * inv);
            *(ushort4*)&Oh[base + dt * 16] = h4;
        }
    }
}

// ---------------------------------------------------------------------------
extern "C" void kernel_launch(void* const* d_in, const int* in_sizes, int n_in,
                              void* d_out, int out_size, void* d_ws, size_t ws_size,
                              hipStream_t stream) {
    const float* x  = (const float*)d_in[0];
    const float* wq = (const float*)d_in[1];
    const float* bq = (const float*)d_in[2];
    const float* wk = (const float*)d_in[3];
    const float* bk = (const float*)d_in[4];
    const float* wv = (const float*)d_in[5];
    const float* bv = (const float*)d_in[6];
    const float* wo = (const float*)d_in[7];
    const float* bo = (const float*)d_in[8];
    float* out = (float*)d_out;

    char* w = (char*)d_ws;
    u16* xh     = (u16*)w;                 w += (size_t)TOKENS * DIM * 2;
    u16* wcat   = (u16*)w;                 w += (size_t)NQKV * DIM * 2;
    u16* woT    = (u16*)w;                 w += (size_t)DIM * DIM * 2;
    u16* qb     = (u16*)w;                 w += (size_t)TOKENS * DIM * 2;
    u16* kb     = (u16*)w;                 w += (size_t)TOKENS * HD * 2;
    u16* vtb    = (u16*)w;                 w += (size_t)TOKENS * HD * 2;
    float* bc   = (float*)w;               w += 16384;
    u16* Oh = xh;   // x dead after QKV GEMM; stream order makes this safe

    const float scale = 0.08838834764831845f;  // 1/sqrt(128)
    const dim3 blk(256);

    conv_f16<<<TOKENS * DIM / 4 / 256, blk, 0, stream>>>(x, xh);
    transpose_f16<<<dim3(DIM / 32, DIM / 32), blk, 0, stream>>>(wq, wcat, DIM, DIM, 0);
    transpose_f16<<<dim3(DIM / 32, HD / 32), blk, 0, stream>>>(wk, wcat, DIM, HD, DIM);
    transpose_f16<<<dim3(DIM / 32, HD / 32), blk, 0, stream>>>(wv, wcat, DIM, HD, DIM + HD);
    transpose_f16<<<dim3(DIM / 32, DIM / 32), blk, 0, stream>>>(wo, woT, DIM, DIM, 0);
    concat_bias<<<NQKV / 256, blk, 0, stream>>>(bq, bk, bv, bc);

    gemm_f16<0><<<dim3(NQKV / 128, TOKENS / 128), blk, 0, stream>>>(
        xh, wcat, bc, nullptr, qb, kb, vtb, scale);

    mqa_attn_f16<<<dim3(SEQ / 128, NH, BATCH), blk, 0, stream>>>(qb, kb, vtb, Oh);

    gemm_f16<1><<<dim3(DIM / 128, TOKENS / 128), blk, 0, stream>>>(
        Oh, woT, bo, out, nullptr, nullptr, nullptr, 1.0f);
}